// Round 5
// baseline (227.607 us; speedup 1.0000x reference)
//
#include <hip/hip_runtime.h>

#define NB 256
#define IN_F 16
#define NGP 4

// ---------------- compile-time algebra tables (NATURAL blade order: idx=mask) ----
namespace alg {
constexpr int popc(int x){int c=0;while(x){c+=x&1;x>>=1;}return c;}
constexpr int qt(int m){return popc(m)&3;}
constexpr int sgn(int a,int b){int s=0;int t=a>>1;while(t){s+=popc(t&b);t>>=1;}return s&1;}
struct Tab {
  unsigned char w[64][64];   // [i][j] -> qt(i)*16 + qt(j)*4 + qt(i^j)
  unsigned char s[64][64];   // [i][j] -> sign of e_i * e_(i^j)
};
constexpr Tab build(){
  Tab t{};
  for(int i=0;i<64;++i)for(int j=0;j<64;++j){
    int k=i^j;
    t.w[i][j]=(unsigned char)(qt(i)*16+qt(j)*4+qt(k));
    t.s[i][j]=(unsigned char)sgn(i,k);
  }
  return t;
}
constexpr Tab T = build();
}

// ---------------- prep: transpose weights into workspace (coalesced READS) ----
// lw_t[((l*4+c)*64+m)*64+f] = gp_lin_w[((l*64+f)*64+m)*4+c]   (65536 floats)
// gpw_t[(l*64+k)*64+f]      = gp_w[(l*64+f)*64+k]             (16384 floats)
// w1t [f2*64+f]             = mlp_w1[f*64+f2]                 ( 4096 floats)
__global__ void ga_prep(const float* __restrict__ gp_lin_w,
                        const float* __restrict__ gp_w,
                        const float* __restrict__ mlp_w1,
                        float* __restrict__ lw_t, float* __restrict__ gpw_t,
                        float* __restrict__ w1t,
                        float* __restrict__ out) {
  const int bx = blockIdx.x, t = threadIdx.x;
  if (bx == 0 && t == 0) out[0] = 0.f;   // mean accumulator init
  if (bx < 256) {
    // block = (l,f); src window [block*256, +256) contiguous -> coalesced read
    const int l = bx >> 6, f = bx & 63;
    const int m = t >> 2, c = t & 3;
    lw_t[((l*4+c)*64 + m)*64 + f] = gp_lin_w[bx*256 + t];
  } else if (bx < 320) {
    // block = (l, f-quad); src window contiguous
    const int b2 = bx - 256;            // 0..63
    const int l = b2 >> 4, f0 = (b2 & 15) * 4;
    const int f = f0 + (t >> 6), k = t & 63;
    gpw_t[(l*64 + k)*64 + f] = gp_w[(l*64 + f0)*64 + t];
  } else {
    const int o = (bx - 320)*256 + t;   // contiguous over mlp_w1
    const int f = o >> 6, f2 = o & 63;
    w1t[f2*64 + f] = mlp_w1[o];
  }
}

// ---------------- GP: thread owns j-quad 4*JQ..4*JQ+3; all indices static ----
// x4/y4 layout: [quad q][channel f][sub s] = blade 4q+s of channel f.
// Key identity: (4ic+a) ^ (4JQ+b) = 4(ic^JQ) + (a^b)  ->  one y-quad per i-quad.
template<int JQ>
__device__ __forceinline__ void gp4(const float* __restrict__ x4,
                                    const float* __restrict__ y4,
                                    const float (&wv)[64], int f, float (&acc)[4]) {
  #pragma unroll
  for (int ic = 0; ic < 16; ++ic) {
    const float4 xv = *(const float4*)(x4 + (ic*64 + f)*4);
    const float4 yv = *(const float4*)(y4 + ((ic^JQ)*64 + f)*4);
    const float xa[4] = {xv.x, xv.y, xv.z, xv.w};
    const float ya[4] = {yv.x, yv.y, yv.z, yv.w};
    #pragma unroll
    for (int b = 0; b < 4; ++b) {
      #pragma unroll
      for (int a = 0; a < 4; ++a) {
        const int i  = 4*ic + a;
        const int j  = 4*JQ + b;
        const int wi = alg::T.w[i][j];
        const float tp = wv[wi] * ya[a^b];
        acc[b] = alg::T.s[i][j] ? fmaf(-tp, xa[a], acc[b])
                                : fmaf( tp, xa[a], acc[b]);
      }
    }
  }
}

// ---------------- main fused kernel: one 1024-thread block per batch element ----
// Occupancy/VGPR shaping (model confirmed R1/R2/R3/R4): the backend budgets
// VGPRs for the LDS-limited occupancy. LDS > 80 KB @1024thr -> 1 block/CU
// -> 16 waves -> 4 waves/EU -> 128-VGPR budget, and the actual launch
// (grid 256 = 1 block/CU) delivers exactly those 16 waves/CU.
__global__ __launch_bounds__(1024) void ga_main(
    const float* __restrict__ points, const float* __restrict__ products,
    const float* __restrict__ lin_w,  const float* __restrict__ lin_b,
    const float* __restrict__ gp_a,
    const float* __restrict__ mlp_b1,
    const float* __restrict__ mlp_w2, const float* __restrict__ mlp_b2,
    const float* __restrict__ lw_t,   const float* __restrict__ gpw_t,
    const float* __restrict__ w1t,
    float* __restrict__ d_out)
{
  __shared__ __align__(16) float x4[16*64*4];   // state,   [quad][f][sub] (16 KB)
  __shared__ __align__(16) float y4[16*64*4];   // lin out, [quad][f][sub] (16 KB)
  __shared__ __align__(16) float red4[16*64*4]; // [jq][f][class] partials (16 KB)
  __shared__ float invn[4*64];                  // [class][f]
  __shared__ float pts[96];
  __shared__ float ynrm[64];
  __shared__ float pad_lds[8448];               // occupancy shaping -> ~84.5 KB total

  const int t  = threadIdx.x;
  const int b  = blockIdx.x;
  const int f  = t & 63;
  const int jq = t >> 6;                        // 0..15, wave-uniform
  const int qj = __builtin_popcount((unsigned)jq) & 3;
  const int cA = qj, cB = (qj+1)&3, cC = (qj+2)&3, cD = (qj+3)&3;

  { volatile float* vp = pad_lds; vp[t] = 0.f; }  // keep pad allocated

  for (int i = t; i < 16*64*4; i += 1024) x4[i] = 0.f;
  if (t < 96) pts[t] = points[b*96 + t];
  __syncthreads();

  // phase 0: embed grade-1 + first qt-linear (blades {0,1,2,4,8,16,32} nonzero)
  if (t < 64) {
    float a[6] = {0,0,0,0,0,0};
    for (int m = 0; m < IN_F; ++m) {
      float lw = lin_w[(t*IN_F+m)*4 + 1];   // qt(grade1)=1
      #pragma unroll
      for (int g = 0; g < 6; ++g) a[g] = fmaf(pts[m*6+g], lw, a[g]);
    }
    x4[(0*64+t)*4+0] = lin_b[t];   // blade 0
    x4[(0*64+t)*4+1] = a[0];       // blade 1
    x4[(0*64+t)*4+2] = a[1];       // blade 2
    x4[(1*64+t)*4+0] = a[2];       // blade 4
    x4[(2*64+t)*4+0] = a[3];       // blade 8
    x4[(4*64+t)*4+0] = a[4];       // blade 16
    x4[(8*64+t)*4+0] = a[5];       // blade 32
  }
  __syncthreads();

  float acc[4];

  for (int l = 0; l < NGP; ++l) {
    // ---- qt-linear: 4 outputs/thread (j = 4*jq+b); classes qj+{0,1,1,2} ----
    float lacc[4] = {0,0,0,0};
    {
      const float* pA = lw_t + (l*4 + cA)*4096 + f;
      const float* pB = lw_t + (l*4 + cB)*4096 + f;
      const float* pC = lw_t + (l*4 + cC)*4096 + f;
      #pragma unroll 8
      for (int m = 0; m < 64; ++m) {
        const float4 xq = *(const float4*)(x4 + (jq*64 + m)*4); // broadcast
        const float wA = pA[m*64], wB = pB[m*64], wC = pC[m*64];
        lacc[0] = fmaf(wA, xq.x, lacc[0]);
        lacc[1] = fmaf(wB, xq.y, lacc[1]);
        lacc[2] = fmaf(wB, xq.z, lacc[2]);
        lacc[3] = fmaf(wC, xq.w, lacc[3]);
      }
    }
    // y-store (b128) + per-class norm partials
    *(float4*)(y4 + (jq*64 + f)*4) = make_float4(lacc[0],lacc[1],lacc[2],lacc[3]);
    red4[(jq*64+f)*4 + cA] = lacc[0]*lacc[0];
    red4[(jq*64+f)*4 + cB] = lacc[1]*lacc[1] + lacc[2]*lacc[2];
    red4[(jq*64+f)*4 + cC] = lacc[3]*lacc[3];
    red4[(jq*64+f)*4 + cD] = 0.f;
    __syncthreads();

    // ---- norms -> folded inverse scales ----
    if (t < 256) {
      const int cc = t >> 6, ff = t & 63;
      float s = 0.f;
      #pragma unroll
      for (int q = 0; q < 16; ++q) s += red4[(q*64+ff)*4 + cc];
      s = fmaxf(s, 1e-12f);
      float nrm = sqrtf(s);
      float av  = gp_a[(l*64+ff)*4 + cc];
      float sig = 1.f/(1.f + expf(-av));
      float nn  = sig*(nrm-1.f) + 1.f;
      invn[cc*64+ff] = 1.f/(nn + 1e-6f);
    }
    __syncthreads();

    // ---- fold norm scales into per-f Cayley weight table (<=48 live regs) ----
    float wv[64];
    {
      const float in0 = invn[0*64+f], in1 = invn[1*64+f],
                  in2 = invn[2*64+f], in3 = invn[3*64+f];
      const float* gw = gpw_t + l*4096 + f;   // [widx][f], coalesced
      #pragma unroll
      for (int wi = 0; wi < 64; ++wi) {
        const float sc = ((wi&3)==0)?in0:(((wi&3)==1)?in1:(((wi&3)==2)?in2:in3));
        wv[wi] = gw[wi*64] * sc;
      }
    }

    // ---- geometric product (all-static via jq-template) ----
    #pragma unroll
    for (int ii = 0; ii < 4; ++ii) acc[ii] = 0.f;
    switch (jq) {
      case  0: gp4< 0>(x4, y4, wv, f, acc); break;
      case  1: gp4< 1>(x4, y4, wv, f, acc); break;
      case  2: gp4< 2>(x4, y4, wv, f, acc); break;
      case  3: gp4< 3>(x4, y4, wv, f, acc); break;
      case  4: gp4< 4>(x4, y4, wv, f, acc); break;
      case  5: gp4< 5>(x4, y4, wv, f, acc); break;
      case  6: gp4< 6>(x4, y4, wv, f, acc); break;
      case  7: gp4< 7>(x4, y4, wv, f, acc); break;
      case  8: gp4< 8>(x4, y4, wv, f, acc); break;
      case  9: gp4< 9>(x4, y4, wv, f, acc); break;
      case 10: gp4<10>(x4, y4, wv, f, acc); break;
      case 11: gp4<11>(x4, y4, wv, f, acc); break;
      case 12: gp4<12>(x4, y4, wv, f, acc); break;
      case 13: gp4<13>(x4, y4, wv, f, acc); break;
      case 14: gp4<14>(x4, y4, wv, f, acc); break;
      default: gp4<15>(x4, y4, wv, f, acc); break;
    }
    __syncthreads();           // all x4/y4 reads done before overwrite
    if (l < NGP-1) {
      *(float4*)(x4 + (jq*64 + f)*4) = make_float4(acc[0],acc[1],acc[2],acc[3]);
    }
    __syncthreads();
  }

  // ---- tail: blade-norm -> MLP -> loss (reuse red4 flat) ----
  float ss = 0.f;
  #pragma unroll
  for (int ii = 0; ii < 4; ++ii) ss = fmaf(acc[ii], acc[ii], ss);
  red4[jq*64+f] = ss;
  __syncthreads();
  if (t < 64) {
    float s = 0.f;
    #pragma unroll
    for (int q = 0; q < 16; ++q) s += red4[q*64+t];
    ynrm[t] = sqrtf(s);
  }
  __syncthreads();
  {
    float hp = 0.f;
    #pragma unroll
    for (int d = 0; d < 4; ++d) {
      const int f2 = 4*jq + d;
      hp = fmaf(w1t[f2*64+f], ynrm[f2], hp);   // coalesced (transposed)
    }
    __syncthreads();                            // ynrm reads done before overwrite
    red4[jq*64+f] = hp;
  }
  __syncthreads();
  if (t < 64) {
    float hpre = mlp_b1[t];
    #pragma unroll
    for (int q = 0; q < 16; ++q) hpre += red4[q*64+t];
    float h = hpre / (1.f + expf(-hpre));   // silu
    float p = h * mlp_w2[t];
    #pragma unroll
    for (int off = 32; off > 0; off >>= 1) p += __shfl_down(p, off, 64);
    if (t == 0) {
      float pred = p + mlp_b2[0];
      float d = pred - products[b];
      float loss = d*d;
      d_out[1+b] = loss;
      atomicAdd(d_out, loss * (1.f/256.f));
    }
  }
}

extern "C" void kernel_launch(void* const* d_in, const int* in_sizes, int n_in,
                              void* d_out, int out_size, void* d_ws, size_t ws_size,
                              hipStream_t stream) {
  const float* points   = (const float*)d_in[0];
  const float* products = (const float*)d_in[1];
  const float* lin_w    = (const float*)d_in[2];
  const float* lin_b    = (const float*)d_in[3];
  const float* gp_lin_w = (const float*)d_in[4];
  const float* gp_a     = (const float*)d_in[5];
  const float* gp_w     = (const float*)d_in[6];
  const float* mlp_w1   = (const float*)d_in[7];
  const float* mlp_b1   = (const float*)d_in[8];
  const float* mlp_w2   = (const float*)d_in[9];
  const float* mlp_b2   = (const float*)d_in[10];
  float* out = (float*)d_out;

  float* lw_t  = (float*)d_ws;        // 65536 floats
  float* gpw_t = lw_t + 65536;        // 16384 floats
  float* w1t   = gpw_t + 16384;       //  4096 floats

  ga_prep<<<336, 256, 0, stream>>>(gp_lin_w, gp_w, mlp_w1, lw_t, gpw_t, w1t, out);
  ga_main<<<NB, 1024, 0, stream>>>(points, products, lin_w, lin_b, gp_a,
                                   mlp_b1, mlp_w2, mlp_b2,
                                   lw_t, gpw_t, w1t, out);
}